// Round 8
// baseline (28.878 us; speedup 1.0000x reference)
//
#include <hip/hip_runtime.h>
#include <hip/hip_bf16.h>

// Decorrelation as a single fused register-only tiny-GEMM kernel.
//   out[n,j] = sum_k A[n,k]*B[k,j],  K=160
//   A[n, k(i,kk)] = u_i^kk * (1-u_i)^(9-kk) * x[n,i]        (NO binomial)
//   B[k(i,kk), j] = i<j  ? binom(9,kk)*params[kk, pair(i,j)]
//                 : i==j ? binom(9,kk)   (sum_kk BIN u^kk v^(9-kk) = 1 -> +x_j)
//                 : 0
// k-axis relabeled so lane (m15,g)'s A-fragment is built from its OWN float4
// (verified R5/R7: any consistent k-bijection on both A and B is correct).
//   lane-local flat index c in [0,40): i = 4g + c/10, kk = c%10
//   MFMA step s consumes halves c = 8s..8s+7.
// B-fragments are rebuilt per wave from params (4.8KB, L2/L3-hot) -- no prep
// kernel, no workspace, one graph node. 4 tiles/wave, loads issued upfront
// for 4KB-in-flight MLP. No LDS, no barriers, no cross-lane ops.

#define DVARS 16
#define KB 10
#define STEPS 5          // K=160 / 32
#define WPB 4            // waves per block (256 threads)
#define TPW 4            // tiles per wave (16 samples each)

typedef _Float16 f16x8 __attribute__((ext_vector_type(8)));
typedef __fp16   h16x2 __attribute__((ext_vector_type(2)));
typedef float    f32x4 __attribute__((ext_vector_type(4)));

static __device__ __forceinline__ unsigned packh2(float a, float b) {
    h16x2 h = __builtin_amdgcn_cvt_pkrtz(a, b);   // a -> low half, b -> high half
    unsigned r;
    __builtin_memcpy(&r, &h, 4);
    return r;
}

__global__ __launch_bounds__(256) void decorr_fused(
        const float* __restrict__ x,
        const float* __restrict__ params,
        const float* __restrict__ prange,
        float* __restrict__ out,
        int nSamples, int nTiles)
{
    int tid  = threadIdx.x;
    int lane = tid & 63;
    int wid  = tid >> 6;
    int g    = lane >> 4;
    int m15  = lane & 15;

    int waveId = blockIdx.x * WPB + wid;
    int t0 = waveId * TPW;
    if (t0 >= nTiles) return;

    // ---- issue all x-tile loads first: 4KB in flight per wave
    float4 xv[TPW];
#pragma unroll
    for (int t = 0; t < TPW; ++t) {
        int row = (t0 + t) * 16 + m15;
        if (row > nSamples - 1) row = nSamples - 1;
        xv[t] = *reinterpret_cast<const float4*>(x + (size_t)row * DVARS + 4 * g);
    }

    // ---- per-wave B fragments straight from params (overlaps with x loads)
    const float BIN[KB] = {1.f, 9.f, 36.f, 84.f, 126.f, 126.f, 84.f, 36.f, 9.f, 1.f};
    int n = m15;                       // this lane's output column
    int tri = n * (n - 1) / 2;
    f16x8 bfr[STEPS];
#pragma unroll
    for (int s = 0; s < STEPS; ++s) {
        unsigned d[4];
#pragma unroll
        for (int h = 0; h < 4; ++h) {
            float w01[2];
#pragma unroll
            for (int e2 = 0; e2 < 2; ++e2) {
                int c  = 8 * s + 2 * h + e2;   // lane-local flat index 0..39
                int i  = 4 * g + c / 10;
                int kk = c % 10;
                int idx = kk * 120 + tri + ((i < n) ? i : 0);   // clamped, safe
                float p = params[idx];
                w01[e2] = (i < n) ? BIN[kk] * p : ((i == n) ? BIN[kk] : 0.f);
            }
            d[h] = packh2(w01[0], w01[1]);
        }
        __builtin_memcpy(&bfr[s], d, 16);
    }

    // ---- normalization constants for this lane's covariate columns i = 4g+q
    float2 li[4];
#pragma unroll
    for (int q = 0; q < 4; ++q) {
        int i = 4 * g + q;
        float lo = prange[i];
        li[q] = make_float2(lo, 1.0f / (prange[DVARS + i] - lo));
    }

    // ---- per tile: build A in registers, 5 MFMAs, store
#pragma unroll
    for (int t = 0; t < TPW; ++t) {
        unsigned afr[STEPS * 4];                        // 20 dwords = 40 halves
        const float* xl = reinterpret_cast<const float*>(&xv[t]);
#pragma unroll
        for (int q = 0; q < 4; ++q) {
            float xm = xl[q];
            float u = (xm - li[q].x) * li[q].y;
            float v = 1.0f - u;
            float vx[KB];
            vx[0] = xm;                                  // vx[k] = v^k * x_i
#pragma unroll
            for (int k = 1; k < KB; ++k) vx[k] = vx[k - 1] * v;
            float tk[KB];
            tk[0] = vx[KB - 1];
            float run = u;
#pragma unroll
            for (int k = 1; k < KB; ++k) {               // tk[k] = u^k v^(9-k) x_i
                tk[k] = run * vx[KB - 1 - k];
                if (k < KB - 1) run *= u;
            }
#pragma unroll
            for (int h = 0; h < 5; ++h)                  // flat half idx c = 10q+2h(+1)
                afr[5 * q + h] = packh2(tk[2 * h], tk[2 * h + 1]);
        }

        f32x4 acc = {0.f, 0.f, 0.f, 0.f};
#pragma unroll
        for (int s = 0; s < STEPS; ++s) {
            f16x8 a;
            __builtin_memcpy(&a, &afr[4 * s], 16);
            acc = __builtin_amdgcn_mfma_f32_16x16x32_f16(a, bfr[s], acc, 0, 0, 0);
        }

        // store: D col = lane&15, row = 4*(lane>>4)+r (verified C/D map)
        int base = (t0 + t) * 16;
#pragma unroll
        for (int r = 0; r < 4; ++r) {
            int sample = base + 4 * g + r;
            if (sample < nSamples)
                out[(size_t)sample * DVARS + m15] = acc[r];
        }
    }
}

extern "C" void kernel_launch(void* const* d_in, const int* in_sizes, int n_in,
                              void* d_out, int out_size, void* d_ws, size_t ws_size,
                              hipStream_t stream) {
    const float* x      = (const float*)d_in[0];   // [N, 16]
    const float* params = (const float*)d_in[1];   // [10, 120]
    const float* prange = (const float*)d_in[2];   // [2, 16]
    float* out = (float*)d_out;

    int nSamples = in_sizes[0] / DVARS;
    int nTiles = (nSamples + 15) / 16;

    int tilesPerBlock = WPB * TPW;                 // 16
    int blocks = (nTiles + tilesPerBlock - 1) / tilesPerBlock;

    decorr_fused<<<blocks, 256, 0, stream>>>(x, params, prange, out,
                                             nSamples, nTiles);
}

// Round 9
// 23.147 us; speedup vs baseline: 1.2476x; 1.2476x over previous
//
#include <hip/hip_runtime.h>
#include <hip/hip_bf16.h>

// Decorrelation as register-only tiny-GEMM per 16-sample tile.
//   out[n,j] = sum_k A[n,k]*B[k,j],  K=160
//   A[n, k(i,kk)] = u_i^kk * (1-u_i)^(9-kk) * x[n,i]        (NO binomial)
//   B[k(i,kk), j] = i<j  ? binom(9,kk)*params[kk, pair(i,j)]
//                 : i==j ? binom(9,kk)   (sum_kk BIN u^kk v^(9-kk) = 1 -> +x_j)
//                 : 0
// k-axis relabeled so lane (m15,g)'s A-fragment is built from its OWN float4
// (verified R5/R7). B-fragments come from a tiny prep kernel via d_ws and are
// loaded with 5 coalesced uint4 per wave (R8's per-wave gather rebuild
// regressed: 40 lane-divergent gathers serialized in the TA).
// Main kernel: 4 consecutive tiles per wave, straight-line, all 4 x-loads
// issued upfront (4KB in flight). No LDS, no barriers, no cross-lane ops.

#define DVARS 16
#define KB 10
#define STEPS 5          // K=160 / 32
#define WPB 4            // waves per block (256 threads)
#define TPW 4            // tiles per wave

typedef _Float16 f16x8 __attribute__((ext_vector_type(8)));
typedef __fp16   h16x2 __attribute__((ext_vector_type(2)));
typedef float    f32x4 __attribute__((ext_vector_type(4)));

static __device__ __forceinline__ unsigned packh2(float a, float b) {
    h16x2 h = __builtin_amdgcn_cvt_pkrtz(a, b);   // a -> low, b -> high
    unsigned r;
    __builtin_memcpy(&r, &h, 4);
    return r;
}

// ws layout: unsigned wsB[5*64*4] (5120 B) then float2 wsLI[16] (128 B)
__global__ void decorr_prep(const float* __restrict__ params,
                            const float* __restrict__ poly_range,
                            unsigned* __restrict__ wsB,
                            float2* __restrict__ wsLI) {
    int t = threadIdx.x;                  // single 512-thread block
    if (t < STEPS * 64) {
        int s = t >> 6;
        int l = t & 63;
        int g = l >> 4;
        int n = l & 15;                   // output column j
        const float BIN[KB] = {1.f, 9.f, 36.f, 84.f, 126.f, 126.f, 84.f, 36.f, 9.f, 1.f};
        float w[8];
        for (int e = 0; e < 8; ++e) {
            int c = 8 * s + e;            // lane-local flat index, 0..39
            int i = 4 * g + c / 10;
            int kk = c % 10;
            float val = 0.f;
            if (i < n)       val = BIN[kk] * params[kk * 120 + (n * (n - 1)) / 2 + i];
            else if (i == n) val = BIN[kk];  // diagonal -> +x_j
            w[e] = val;
        }
        for (int cc = 0; cc < 4; ++cc)
            wsB[t * 4 + cc] = packh2(w[2 * cc], w[2 * cc + 1]);
    }
    if (t < DVARS) {
        float lo = poly_range[t];
        float hi = poly_range[DVARS + t];
        wsLI[t] = make_float2(lo, 1.0f / (hi - lo));
    }
}

__global__ __launch_bounds__(256) void decorr_main(
        const float* __restrict__ x,
        const uint4* __restrict__ wsB,
        const float2* __restrict__ wsLI,
        float* __restrict__ out,
        int nSamples, int nTiles)
{
    int tid  = threadIdx.x;
    int lane = tid & 63;
    int wid  = tid >> 6;
    int g    = lane >> 4;
    int m15  = lane & 15;

    int t0 = (blockIdx.x * WPB + wid) * TPW;
    if (t0 >= nTiles) return;

    // ---- issue all x-tile loads first: 4KB in flight per wave
    float4 xv[TPW];
#pragma unroll
    for (int t = 0; t < TPW; ++t) {
        int row = (t0 + t) * 16 + m15;
        if (row > nSamples - 1) row = nSamples - 1;
        xv[t] = *reinterpret_cast<const float4*>(x + (size_t)row * DVARS + 4 * g);
    }

    // ---- B fragments: 5 coalesced uint4 loads, live in VGPRs throughout
    f16x8 bfr[STEPS];
#pragma unroll
    for (int s = 0; s < STEPS; ++s) {
        uint4 raw = wsB[s * 64 + lane];
        __builtin_memcpy(&bfr[s], &raw, 16);
    }
    // normalization constants for this lane's covariate columns i = 4g+q
    float2 li[4];
#pragma unroll
    for (int q = 0; q < 4; ++q) li[q] = wsLI[4 * g + q];

    // ---- per tile: build A in registers, 5 MFMAs, store
#pragma unroll
    for (int t = 0; t < TPW; ++t) {
        unsigned afr[STEPS * 4];                        // 20 dwords = 40 halves
        const float* xl = reinterpret_cast<const float*>(&xv[t]);
#pragma unroll
        for (int q = 0; q < 4; ++q) {
            float xm = xl[q];
            float u = (xm - li[q].x) * li[q].y;
            float v = 1.0f - u;
            float vx[KB];
            vx[0] = xm;                                  // vx[k] = v^k * x_i
#pragma unroll
            for (int k = 1; k < KB; ++k) vx[k] = vx[k - 1] * v;
            float tk[KB];
            tk[0] = vx[KB - 1];
            float run = u;
#pragma unroll
            for (int k = 1; k < KB; ++k) {               // tk[k] = u^k v^(9-k) x_i
                tk[k] = run * vx[KB - 1 - k];
                if (k < KB - 1) run *= u;
            }
#pragma unroll
            for (int h = 0; h < 5; ++h)                  // flat half idx c = 10q+2h(+1)
                afr[5 * q + h] = packh2(tk[2 * h], tk[2 * h + 1]);
        }

        f32x4 acc = {0.f, 0.f, 0.f, 0.f};
#pragma unroll
        for (int s = 0; s < STEPS; ++s) {
            f16x8 a;
            __builtin_memcpy(&a, &afr[4 * s], 16);
            acc = __builtin_amdgcn_mfma_f32_16x16x32_f16(a, bfr[s], acc, 0, 0, 0);
        }

        // store: D col = lane&15, row = 4*(lane>>4)+r (verified C/D map)
        int base = (t0 + t) * 16;
#pragma unroll
        for (int r = 0; r < 4; ++r) {
            int sample = base + 4 * g + r;
            if (sample < nSamples)
                out[(size_t)sample * DVARS + m15] = acc[r];
        }
    }
}

extern "C" void kernel_launch(void* const* d_in, const int* in_sizes, int n_in,
                              void* d_out, int out_size, void* d_ws, size_t ws_size,
                              hipStream_t stream) {
    const float* x      = (const float*)d_in[0];   // [N, 16]
    const float* params = (const float*)d_in[1];   // [10, 120]
    const float* prange = (const float*)d_in[2];   // [2, 16]
    float* out = (float*)d_out;

    int nSamples = in_sizes[0] / DVARS;
    int nTiles = (nSamples + 15) / 16;

    unsigned* wsB = (unsigned*)d_ws;
    float2* wsLI  = (float2*)((char*)d_ws + STEPS * 64 * 16);

    decorr_prep<<<1, 512, 0, stream>>>(params, prange, wsB, wsLI);

    int tilesPerBlock = WPB * TPW;                 // 16
    int blocks = (nTiles + tilesPerBlock - 1) / tilesPerBlock;

    decorr_main<<<blocks, 256, 0, stream>>>(x, (const uint4*)wsB, wsLI, out,
                                            nSamples, nTiles);
}

// Round 10
// 22.711 us; speedup vs baseline: 1.2716x; 1.0192x over previous
//
#include <hip/hip_runtime.h>
#include <hip/hip_bf16.h>

// Decorrelation, single fused kernel, register-only tiny-GEMM per 16-sample tile.
//   out[n,j] = sum_k A[n,k]*B[k,j],  K=160
//   A[n, k(i,kk)] = u_i^kk * (1-u_i)^(9-kk) * x[n,i]        (NO binomial)
//   B[k(i,kk), j] = i<j  ? binom(9,kk)*params[kk, pair(i,j)]
//                 : i==j ? binom(9,kk)   (sum_kk BIN u^kk v^(9-kk) = 1 -> +x_j)
//                 : 0
// k-axis relabeled so lane (m15,g)'s A-fragment is built from its OWN float4
// (verified R5/R7/R9: any consistent k-bijection on both A and B is correct).
//   lane-local flat index c in [0,40): i = 4g + c/10, kk = c%10
//
// vs R9: prep kernel + d_ws removed (one graph node). params staged into LDS
// with coalesced loads (R8's regression was per-lane GLOBAL gathers; LDS
// gathers amortized over 32 tiles/block are cheap). 8 tiles/wave with all
// x-loads issued upfront (8KB MLP/wave). Bernstein chain packed as v2f ->
// v_pk_mul_f32 (R3-verified VOP3P packing) to halve basis VALU issue.

#define DVARS 16
#define KB 10
#define STEPS 5          // K=160 / 32
#define WPB 4            // waves per block (256 threads)
#define TPW 8            // tiles per wave

typedef _Float16 f16x8 __attribute__((ext_vector_type(8)));
typedef __fp16   h16x2 __attribute__((ext_vector_type(2)));
typedef float    f32x4 __attribute__((ext_vector_type(4)));
typedef float    v2f   __attribute__((ext_vector_type(2)));

static __device__ __forceinline__ unsigned packh2(float a, float b) {
    h16x2 h = __builtin_amdgcn_cvt_pkrtz(a, b);   // a -> low, b -> high
    unsigned r;
    __builtin_memcpy(&r, &h, 4);
    return r;
}

__global__ __launch_bounds__(256) void decorr_fused(
        const float* __restrict__ x,
        const float* __restrict__ params,
        const float* __restrict__ prange,
        float* __restrict__ out,
        int nSamples, int nTiles)
{
    __shared__ float  Ps[KB * 120];      // 4.8 KB params table
    __shared__ float2 LIs[DVARS];

    int tid  = threadIdx.x;
    int lane = tid & 63;
    int wid  = tid >> 6;
    int g    = lane >> 4;
    int m15  = lane & 15;

    int t0 = (blockIdx.x * WPB + wid) * TPW;

    // ---- issue ALL x-tile loads first: 8KB in flight per wave
    float4 xv[TPW];
#pragma unroll
    for (int t = 0; t < TPW; ++t) {
        int row = (t0 + t) * 16 + m15;
        if (row > nSamples - 1) row = nSamples - 1;   // tail clamp (loads only)
        xv[t] = *reinterpret_cast<const float4*>(x + (size_t)row * DVARS + 4 * g);
    }

    // ---- stage params into LDS, coalesced (overlaps with x loads in flight)
    for (int idx = tid; idx < KB * 120; idx += 256) Ps[idx] = params[idx];
    if (tid < DVARS) {
        float lo = prange[tid];
        LIs[tid] = make_float2(lo, 1.0f / (prange[DVARS + tid] - lo));
    }
    __syncthreads();

    // ---- B fragments from LDS gathers (once per wave, amortized 8 tiles)
    const float BIN[KB] = {1.f, 9.f, 36.f, 84.f, 126.f, 126.f, 84.f, 36.f, 9.f, 1.f};
    int n = m15;                        // this lane's output column
    int tri = n * (n - 1) / 2;
    f16x8 bfr[STEPS];
#pragma unroll
    for (int s = 0; s < STEPS; ++s) {
        unsigned d[4];
#pragma unroll
        for (int h = 0; h < 4; ++h) {
            float w01[2];
#pragma unroll
            for (int e2 = 0; e2 < 2; ++e2) {
                int c  = 8 * s + 2 * h + e2;     // lane-local flat index 0..39
                int i  = 4 * g + c / 10;
                int kk = c % 10;
                int idx = kk * 120 + tri + ((i < n) ? i : 0);   // clamped: in-bounds
                float p = Ps[idx];
                w01[e2] = (i < n) ? BIN[kk] * p : ((i == n) ? BIN[kk] : 0.f);
            }
            d[h] = packh2(w01[0], w01[1]);
        }
        __builtin_memcpy(&bfr[s], d, 16);
    }

    // ---- normalization constants, packed for the v2f basis chain
    v2f lo2[2], inv2[2];
#pragma unroll
    for (int p = 0; p < 2; ++p) {
        float2 a = LIs[4 * g + 2 * p];
        float2 b = LIs[4 * g + 2 * p + 1];
        lo2[p]  = (v2f){a.x, b.x};
        inv2[p] = (v2f){a.y, b.y};
    }

    // ---- per tile: packed basis build, 5 MFMAs, store
#pragma unroll
    for (int t = 0; t < TPW; ++t) {
        if (t0 + t >= nTiles) break;              // wave-uniform tail exit

        unsigned afr[STEPS * 4];                  // 20 dwords = 40 halves
        const float* xl = reinterpret_cast<const float*>(&xv[t]);
#pragma unroll
        for (int p = 0; p < 2; ++p) {             // covariate pair q = (2p, 2p+1)
            v2f xm = (v2f){xl[2 * p], xl[2 * p + 1]};
            v2f u = (xm - lo2[p]) * inv2[p];
            v2f v = (v2f){1.f, 1.f} - u;
            v2f vx[KB];
            vx[0] = xm;                            // vx[k] = v^k * x_i
#pragma unroll
            for (int k = 1; k < KB; ++k) vx[k] = vx[k - 1] * v;
            v2f tk[KB];
            tk[0] = vx[KB - 1];
            v2f run = u;
#pragma unroll
            for (int k = 1; k < KB; ++k) {         // tk[k] = u^k v^(9-k) x_i
                tk[k] = run * vx[KB - 1 - k];
                if (k < KB - 1) run = run * u;
            }
#pragma unroll
            for (int h = 0; h < 5; ++h) {          // afr[5q+h] = halves (10q+2h, +1)
                afr[5 * (2 * p)     + h] = packh2(tk[2 * h].x, tk[2 * h + 1].x);
                afr[5 * (2 * p + 1) + h] = packh2(tk[2 * h].y, tk[2 * h + 1].y);
            }
        }

        f32x4 acc = {0.f, 0.f, 0.f, 0.f};
#pragma unroll
        for (int s = 0; s < STEPS; ++s) {
            f16x8 a;
            __builtin_memcpy(&a, &afr[4 * s], 16);
            acc = __builtin_amdgcn_mfma_f32_16x16x32_f16(a, bfr[s], acc, 0, 0, 0);
        }

        // store: D col = lane&15, row = 4*(lane>>4)+r (verified C/D map)
        int base = (t0 + t) * 16;
        if (base + 16 <= nSamples) {               // full tile: unguarded stores
#pragma unroll
            for (int r = 0; r < 4; ++r)
                out[(size_t)(base + 4 * g + r) * DVARS + m15] = acc[r];
        } else {
#pragma unroll
            for (int r = 0; r < 4; ++r) {
                int sample = base + 4 * g + r;
                if (sample < nSamples)
                    out[(size_t)sample * DVARS + m15] = acc[r];
            }
        }
    }
}

extern "C" void kernel_launch(void* const* d_in, const int* in_sizes, int n_in,
                              void* d_out, int out_size, void* d_ws, size_t ws_size,
                              hipStream_t stream) {
    const float* x      = (const float*)d_in[0];   // [N, 16]
    const float* params = (const float*)d_in[1];   // [10, 120]
    const float* prange = (const float*)d_in[2];   // [2, 16]
    float* out = (float*)d_out;

    int nSamples = in_sizes[0] / DVARS;
    int nTiles = (nSamples + 15) / 16;

    int tilesPerBlock = WPB * TPW;                 // 32
    int blocks = (nTiles + tilesPerBlock - 1) / tilesPerBlock;

    decorr_fused<<<blocks, 256, 0, stream>>>(x, params, prange, out,
                                             nSamples, nTiles);
}

// Round 11
// 21.918 us; speedup vs baseline: 1.3175x; 1.0361x over previous
//
#include <hip/hip_runtime.h>
#include <hip/hip_bf16.h>

// Decorrelation, single fused kernel, register-only tiny-GEMM per 16-sample tile.
//   out[n,j] = sum_k A[n,k]*B[k,j],  K=160
//   A[n, k(i,kk)] = u_i^kk * (1-u_i)^(9-kk) * x[n,i]        (NO binomial)
//   B[k(i,kk), j] = i<j  ? binom(9,kk)*params[kk, pair(i,j)]
//                 : i==j ? binom(9,kk)   (sum_kk BIN u^kk v^(9-kk) = 1 -> +x_j)
//                 : 0
// k-axis relabeled so lane (m15,g)'s A-fragment is built from its OWN float4
// (verified R5/R7/R9/R10: any consistent k-bijection on both operands is
// correct; both mfma operands use the identical (lane,elem)->k map).
//
// vs R10: OPERAND-SWAPPED MFMA -- mfma(bfr, afr) computes D^T, so each lane
// holds out[sample = base+m15, j = 4g..4g+3]: 16B contiguous -> ONE
// global_store_dwordx4 per tile (was 4 strided store_dword). 1KB contiguous
// per store instruction, mirroring the load pattern.

#define DVARS 16
#define KB 10
#define STEPS 5          // K=160 / 32
#define WPB 4            // waves per block (256 threads)
#define TPW 8            // tiles per wave

typedef _Float16 f16x8 __attribute__((ext_vector_type(8)));
typedef __fp16   h16x2 __attribute__((ext_vector_type(2)));
typedef float    f32x4 __attribute__((ext_vector_type(4)));
typedef float    v2f   __attribute__((ext_vector_type(2)));

static __device__ __forceinline__ unsigned packh2(float a, float b) {
    h16x2 h = __builtin_amdgcn_cvt_pkrtz(a, b);   // a -> low, b -> high
    unsigned r;
    __builtin_memcpy(&r, &h, 4);
    return r;
}

__global__ __launch_bounds__(256) void decorr_fused(
        const float* __restrict__ x,
        const float* __restrict__ params,
        const float* __restrict__ prange,
        float* __restrict__ out,
        int nSamples, int nTiles)
{
    __shared__ float  Ps[KB * 120];      // 4.8 KB params table
    __shared__ float2 LIs[DVARS];

    int tid  = threadIdx.x;
    int lane = tid & 63;
    int wid  = tid >> 6;
    int g    = lane >> 4;
    int m15  = lane & 15;

    int t0 = (blockIdx.x * WPB + wid) * TPW;

    // ---- issue ALL x-tile loads first: 8KB in flight per wave
    float4 xv[TPW];
#pragma unroll
    for (int t = 0; t < TPW; ++t) {
        int row = (t0 + t) * 16 + m15;
        if (row > nSamples - 1) row = nSamples - 1;   // tail clamp (loads only)
        xv[t] = *reinterpret_cast<const float4*>(x + (size_t)row * DVARS + 4 * g);
    }

    // ---- stage params into LDS, coalesced (overlaps with x loads in flight)
    for (int idx = tid; idx < KB * 120; idx += 256) Ps[idx] = params[idx];
    if (tid < DVARS) {
        float lo = prange[tid];
        LIs[tid] = make_float2(lo, 1.0f / (prange[DVARS + tid] - lo));
    }
    __syncthreads();

    // ---- B fragments from LDS gathers (once per wave, amortized 8 tiles)
    const float BIN[KB] = {1.f, 9.f, 36.f, 84.f, 126.f, 126.f, 84.f, 36.f, 9.f, 1.f};
    int n = m15;                        // this lane's output column j
    int tri = n * (n - 1) / 2;
    f16x8 bfr[STEPS];
#pragma unroll
    for (int s = 0; s < STEPS; ++s) {
        unsigned d[4];
#pragma unroll
        for (int h = 0; h < 4; ++h) {
            float w01[2];
#pragma unroll
            for (int e2 = 0; e2 < 2; ++e2) {
                int c  = 8 * s + 2 * h + e2;     // lane-local flat index 0..39
                int i  = 4 * g + c / 10;
                int kk = c % 10;
                int idx = kk * 120 + tri + ((i < n) ? i : 0);   // clamped: in-bounds
                float p = Ps[idx];
                w01[e2] = (i < n) ? BIN[kk] * p : ((i == n) ? BIN[kk] : 0.f);
            }
            d[h] = packh2(w01[0], w01[1]);
        }
        __builtin_memcpy(&bfr[s], d, 16);
    }

    // ---- normalization constants, packed for the v2f basis chain
    v2f lo2[2], inv2[2];
#pragma unroll
    for (int p = 0; p < 2; ++p) {
        float2 a = LIs[4 * g + 2 * p];
        float2 b = LIs[4 * g + 2 * p + 1];
        lo2[p]  = (v2f){a.x, b.x};
        inv2[p] = (v2f){a.y, b.y};
    }

    // ---- per tile: packed basis build, 5 operand-swapped MFMAs, float4 store
#pragma unroll
    for (int t = 0; t < TPW; ++t) {
        if (t0 + t >= nTiles) break;              // wave-uniform tail exit

        unsigned afr[STEPS * 4];                  // 20 dwords = 40 halves
        const float* xl = reinterpret_cast<const float*>(&xv[t]);
#pragma unroll
        for (int p = 0; p < 2; ++p) {             // covariate pair q = (2p, 2p+1)
            v2f xm = (v2f){xl[2 * p], xl[2 * p + 1]};
            v2f u = (xm - lo2[p]) * inv2[p];
            v2f v = (v2f){1.f, 1.f} - u;
            v2f vx[KB];
            vx[0] = xm;                            // vx[k] = v^k * x_i
#pragma unroll
            for (int k = 1; k < KB; ++k) vx[k] = vx[k - 1] * v;
            v2f tk[KB];
            tk[0] = vx[KB - 1];
            v2f run = u;
#pragma unroll
            for (int k = 1; k < KB; ++k) {         // tk[k] = u^k v^(9-k) x_i
                tk[k] = run * vx[KB - 1 - k];
                if (k < KB - 1) run = run * u;
            }
#pragma unroll
            for (int h = 0; h < 5; ++h) {          // afr[5q+h] = halves (10q+2h, +1)
                afr[5 * (2 * p)     + h] = packh2(tk[2 * h].x, tk[2 * h + 1].x);
                afr[5 * (2 * p + 1) + h] = packh2(tk[2 * h].y, tk[2 * h + 1].y);
            }
        }

        f32x4 acc = {0.f, 0.f, 0.f, 0.f};
#pragma unroll
        for (int s = 0; s < STEPS; ++s) {
            f16x8 a;
            __builtin_memcpy(&a, &afr[4 * s], 16);
            // swapped operands: D^T -> lane holds out[base+m15, 4g..4g+3]
            acc = __builtin_amdgcn_mfma_f32_16x16x32_f16(bfr[s], a, acc, 0, 0, 0);
        }

        int base = (t0 + t) * 16;
        int sample = base + m15;
        if (sample < nSamples) {
            float4 o = make_float4(acc[0], acc[1], acc[2], acc[3]);
            *reinterpret_cast<float4*>(out + (size_t)sample * DVARS + 4 * g) = o;
        }
    }
}

extern "C" void kernel_launch(void* const* d_in, const int* in_sizes, int n_in,
                              void* d_out, int out_size, void* d_ws, size_t ws_size,
                              hipStream_t stream) {
    const float* x      = (const float*)d_in[0];   // [N, 16]
    const float* params = (const float*)d_in[1];   // [10, 120]
    const float* prange = (const float*)d_in[2];   // [2, 16]
    float* out = (float*)d_out;

    int nSamples = in_sizes[0] / DVARS;
    int nTiles = (nSamples + 15) / 16;

    int tilesPerBlock = WPB * TPW;                 // 32
    int blocks = (nTiles + tilesPerBlock - 1) / tilesPerBlock;

    decorr_fused<<<blocks, 256, 0, stream>>>(x, params, prange, out,
                                             nSamples, nTiles);
}

// Round 13
// 18.222 us; speedup vs baseline: 1.5848x; 1.2028x over previous
//
#include <hip/hip_runtime.h>
#include <hip/hip_bf16.h>

// Decorrelation, single fused kernel, register-only tiny-GEMM per 16-sample tile.
//   out[n,j] = sum_k A[n,k]*B[k,j],  K=160
//   A[n, k(i,kk)] = u_i^kk * (1-u_i)^(9-kk) * x[n,i]        (NO binomial)
//   B[k(i,kk), j] = i<j  ? binom(9,kk)*params[kk, pair(i,j)]
//                 : i==j ? binom(9,kk)   (sum_kk BIN u^kk v^(9-kk) = 1 -> +x_j)
//                 : 0
// k-axis relabeled so lane (m15,g)'s A-fragment is built from its OWN float4
// (verified R5..R11). Operand-swapped MFMA (R11): mfma(bfr, afr) -> lane holds
// out[base+m15, 4g..4g+3], one global_store_dwordx4 per tile.
//
// vs R11: BARRIER REORDER -- params->LDS + barrier FIRST, x-loads AFTER the
// barrier so the barrier's vmcnt(0) drain never touches them; they overlap
// B-build and drain via fine-grained per-consumer vmcnt. NT stores via native
// ext_vector f32x4 (HIP float4 class type rejected by the builtin, R12).

#define DVARS 16
#define KB 10
#define STEPS 5          // K=160 / 32
#define WPB 4            // waves per block (256 threads)
#define TPW 8            // tiles per wave

typedef _Float16 f16x8 __attribute__((ext_vector_type(8)));
typedef __fp16   h16x2 __attribute__((ext_vector_type(2)));
typedef float    f32x4 __attribute__((ext_vector_type(4)));
typedef float    v2f   __attribute__((ext_vector_type(2)));

static __device__ __forceinline__ unsigned packh2(float a, float b) {
    h16x2 h = __builtin_amdgcn_cvt_pkrtz(a, b);   // a -> low, b -> high
    unsigned r;
    __builtin_memcpy(&r, &h, 4);
    return r;
}

__global__ __launch_bounds__(256) void decorr_fused(
        const float* __restrict__ x,
        const float* __restrict__ params,
        const float* __restrict__ prange,
        float* __restrict__ out,
        int nSamples, int nTiles)
{
    __shared__ float  Ps[KB * 120];      // 4.8 KB params table
    __shared__ float2 LIs[DVARS];

    int tid  = threadIdx.x;
    int lane = tid & 63;
    int wid  = tid >> 6;
    int g    = lane >> 4;
    int m15  = lane & 15;

    int t0 = (blockIdx.x * WPB + wid) * TPW;

    // ---- stage params into LDS FIRST, then barrier (x-loads come after, so
    //      the barrier's vmcnt(0) drain never touches them)
    for (int idx = tid; idx < KB * 120; idx += 256) Ps[idx] = params[idx];
    if (tid < DVARS) {
        float lo = prange[tid];
        LIs[tid] = make_float2(lo, 1.0f / (prange[DVARS + tid] - lo));
    }
    __syncthreads();

    // ---- issue ALL x-tile loads now: 8KB in flight, overlapping B-build
    float4 xv[TPW];
#pragma unroll
    for (int t = 0; t < TPW; ++t) {
        int row = (t0 + t) * 16 + m15;
        if (row > nSamples - 1) row = nSamples - 1;   // tail clamp (loads only)
        xv[t] = *reinterpret_cast<const float4*>(x + (size_t)row * DVARS + 4 * g);
    }

    // ---- B fragments from LDS gathers (once per wave, amortized 8 tiles)
    const float BIN[KB] = {1.f, 9.f, 36.f, 84.f, 126.f, 126.f, 84.f, 36.f, 9.f, 1.f};
    int n = m15;                        // this lane's output column j
    int tri = n * (n - 1) / 2;
    f16x8 bfr[STEPS];
#pragma unroll
    for (int s = 0; s < STEPS; ++s) {
        unsigned d[4];
#pragma unroll
        for (int h = 0; h < 4; ++h) {
            float w01[2];
#pragma unroll
            for (int e2 = 0; e2 < 2; ++e2) {
                int c  = 8 * s + 2 * h + e2;     // lane-local flat index 0..39
                int i  = 4 * g + c / 10;
                int kk = c % 10;
                int idx = kk * 120 + tri + ((i < n) ? i : 0);   // clamped: in-bounds
                float p = Ps[idx];
                w01[e2] = (i < n) ? BIN[kk] * p : ((i == n) ? BIN[kk] : 0.f);
            }
            d[h] = packh2(w01[0], w01[1]);
        }
        __builtin_memcpy(&bfr[s], d, 16);
    }

    // ---- normalization constants, packed for the v2f basis chain
    v2f lo2[2], inv2[2];
#pragma unroll
    for (int p = 0; p < 2; ++p) {
        float2 a = LIs[4 * g + 2 * p];
        float2 b = LIs[4 * g + 2 * p + 1];
        lo2[p]  = (v2f){a.x, b.x};
        inv2[p] = (v2f){a.y, b.y};
    }

    // ---- per tile: packed basis build, 5 operand-swapped MFMAs, NT float4 store
#pragma unroll
    for (int t = 0; t < TPW; ++t) {
        unsigned afr[STEPS * 4];                  // 20 dwords = 40 halves
        const float* xl = reinterpret_cast<const float*>(&xv[t]);
#pragma unroll
        for (int p = 0; p < 2; ++p) {             // covariate pair q = (2p, 2p+1)
            v2f xm = (v2f){xl[2 * p], xl[2 * p + 1]};
            v2f u = (xm - lo2[p]) * inv2[p];
            v2f v = (v2f){1.f, 1.f} - u;
            v2f vx[KB];
            vx[0] = xm;                            // vx[k] = v^k * x_i
#pragma unroll
            for (int k = 1; k < KB; ++k) vx[k] = vx[k - 1] * v;
            v2f tk[KB];
            tk[0] = vx[KB - 1];
            v2f run = u;
#pragma unroll
            for (int k = 1; k < KB; ++k) {         // tk[k] = u^k v^(9-k) x_i
                tk[k] = run * vx[KB - 1 - k];
                if (k < KB - 1) run = run * u;
            }
#pragma unroll
            for (int h = 0; h < 5; ++h) {          // afr[5q+h] = halves (10q+2h, +1)
                afr[5 * (2 * p)     + h] = packh2(tk[2 * h].x, tk[2 * h + 1].x);
                afr[5 * (2 * p + 1) + h] = packh2(tk[2 * h].y, tk[2 * h + 1].y);
            }
        }

        f32x4 acc = {0.f, 0.f, 0.f, 0.f};
#pragma unroll
        for (int s = 0; s < STEPS; ++s) {
            f16x8 a;
            __builtin_memcpy(&a, &afr[4 * s], 16);
            // swapped operands: D^T -> lane holds out[base+m15, 4g..4g+3]
            acc = __builtin_amdgcn_mfma_f32_16x16x32_f16(bfr[s], a, acc, 0, 0, 0);
        }

        int sample = (t0 + t) * 16 + m15;
        if (sample < nSamples) {
            __builtin_nontemporal_store(
                acc, reinterpret_cast<f32x4*>(out + (size_t)sample * DVARS + 4 * g));
        }
    }
}

extern "C" void kernel_launch(void* const* d_in, const int* in_sizes, int n_in,
                              void* d_out, int out_size, void* d_ws, size_t ws_size,
                              hipStream_t stream) {
    const float* x      = (const float*)d_in[0];   // [N, 16]
    const float* params = (const float*)d_in[1];   // [10, 120]
    const float* prange = (const float*)d_in[2];   // [2, 16]
    float* out = (float*)d_out;

    int nSamples = in_sizes[0] / DVARS;
    int nTiles = (nSamples + 15) / 16;

    int tilesPerBlock = WPB * TPW;                 // 32
    int blocks = (nTiles + tilesPerBlock - 1) / tilesPerBlock;

    decorr_fused<<<blocks, 256, 0, stream>>>(x, params, prange, out,
                                             nSamples, nTiles);
}